// Round 6
// baseline (243.475 us; speedup 1.0000x reference)
//
#include <hip/hip_runtime.h>

// EdgeAttention: 4-scale 1x1-conv projection + pairwise per-pixel cosine + 4x4 softmax.
// Round 6:
//  - proj: fragment-linear W packing -> LDS staging is a contiguous 16KB copy and
//    A-fragment reads are canonical base+lane*16 ds_read_b128. LDS 36.9 -> 20.5 KB
//    (two-pass transpose epilogue) to raise co-residency (r5 Occupancy was 15%).
//  - pair pass: cell_dots — one block per (b, scale-3 cell); reads the 8x8 u0 patch,
//    4x4 u1, 2x2 u2, 1 u3 pixel exactly once (coalesced) and computes all 6 pair dot
//    sums in registers. Replaces r5 pair_dots (125 MB, 4x re-reads) with 67 MB single-touch.
// Nearest upsample == block replication (src = dst >> d): pair (i,j) mean over finer grid.
// Diagonal attn == 1 exactly.

#define CCH 256

typedef __attribute__((ext_vector_type(8))) short short8;
typedef __attribute__((ext_vector_type(4))) short short4_;
typedef __attribute__((ext_vector_type(4))) float float4_;

__device__ inline short f2bf(float x) {   // round-to-nearest-even fp32 -> bf16
    union { float f; unsigned u; } c; c.f = x;
    unsigned u = c.u + 0x7FFFu + ((c.u >> 16) & 1u);
    return (short)(u >> 16);
}
__device__ inline float bf2f(short b) {
    union { unsigned u; float f; } c; c.u = ((unsigned)(unsigned short)b) << 16;
    return c.f;
}

// ---------- W pack: fp32 [o][c] -> bf16 fragment-linear ----------
// Element (o,c): ks=c>>5, quad=(c&31)>>3, e=c&7, mt=o>>4, ln=o&15.
// pos = ks*8192 + mt*512 + (quad*16+ln)*8 + e  -> afrag(mt) = base + lane*16B contiguous.
__global__ void pack_w(const float* __restrict__ w0, const float* __restrict__ w1,
                       const float* __restrict__ w2, const float* __restrict__ w3,
                       short* __restrict__ wp) {
    const float* W[4] = {w0, w1, w2, w3};
    const float* Ws = W[blockIdx.y];
    short* out = wp + (size_t)blockIdx.y * 65536;
    int id = blockIdx.x * 256 + threadIdx.x;   // 0..8191 short8s
    int ks = id >> 10;
    int rest = id & 1023;
    int mt = rest >> 6;
    int fl = rest & 63;          // fragment lane = quad*16 + ln
    int ln = fl & 15, quad = fl >> 4;
    const float* src = Ws + (mt * 16 + ln) * CCH + ks * 32 + quad * 8;
    short8 v;
#pragma unroll
    for (int j = 0; j < 8; ++j) v[j] = f2bf(src[j]);
    *(short8*)(out + (size_t)id * 8) = v;
}

// ---------- Projection GEMM (bf16 MFMA, LDS-staged) + bias + normalize + transpose ----
// 256 thr = 4 waves; block computes 256 out-ch for 64 pixels of one (scale,b).
// Wt/Ft are in MFMA fragment order: frag = LDSbase + lane*16B (canonical pattern).
#define TPITCH 264   // transpose pitch in shorts (256 + 8 pad)
__global__ __launch_bounds__(256) void proj_norm(
    const float* __restrict__ f0, const float* __restrict__ f1,
    const float* __restrict__ f2, const float* __restrict__ f3,
    const short* __restrict__ wp,
    const float* __restrict__ b0, const float* __restrict__ b1,
    const float* __restrict__ b2, const float* __restrict__ b3,
    short* __restrict__ u0, short* __restrict__ u1,
    short* __restrict__ u2, short* __restrict__ u3)
{
    __shared__ __align__(16) char smem[20992];
    short* Wt = (short*)smem;                 // 16384 B, fragment-linear
    short* Ft = (short*)(smem + 16384);       //  4096 B, fragment-linear
    short* Ut = (short*)smem;                 // epilogue alias: [32][TPITCH] = 16896 B

    const int blk = blockIdx.x;
    int s, b, tile, L;
    const float* F; const float* bias; short* U;
    if (blk < 800)       { s = 0; int r = blk;        b = r / 100; tile = r % 100; L = 6400; F = f0; bias = b0; U = u0; }
    else if (blk < 1000) { s = 1; int r = blk - 800;  b = r / 25;  tile = r % 25;  L = 1600; F = f1; bias = b1; U = u1; }
    else if (blk < 1056) { s = 2; int r = blk - 1000; b = r / 7;   tile = r % 7;   L = 400;  F = f2; bias = b2; U = u2; }
    else                 { s = 3; int r = blk - 1056; b = r / 2;   tile = r % 2;   L = 100;  F = f3; bias = b3; U = u3; }

    const int t    = threadIdx.x;
    const int lane = t & 63;
    const int wav  = t >> 6;
    const int ln   = lane & 15;
    const int quad = lane >> 4;
    const int pixbase = tile * 64;
    const float* Fb = F + (size_t)b * CCH * L;
    const short* wbase = wp + (size_t)s * 65536;

    float4_ acc[16];
#pragma unroll
    for (int i = 0; i < 16; ++i) acc[i] = (float4_){0.f, 0.f, 0.f, 0.f};

    // F staging: thread loads 8 channels (chunk fchunk) of pixel fpix, writes its
    // short8 into fragment order: wave (fpix>>4), frag-lane = fchunk*16 + (fpix&15).
    const int fpix = t & 63;
    const int fchunk = t >> 6;
    const int gpix0 = pixbase + fpix;
    const bool pin = gpix0 < L;
    const int gl0 = pin ? gpix0 : 0;
    short* fdst = Ft + (fpix >> 4) * 512 + (fchunk * 16 + (fpix & 15)) * 8;

    for (int ks = 0; ks < 8; ++ks) {
        __syncthreads();
        // W slice: straight contiguous 16 KB copy (pre-packed fragment-linear).
        {
            const short8* src = (const short8*)(wbase + ks * 8192);
            short8* dst = (short8*)Wt;
#pragma unroll
            for (int it = 0; it < 4; ++it) {
                int idx = it * 256 + t;
                dst[idx] = src[idx];
            }
        }
        // F slice: fp32 -> bf16 on the fly, fragment-order store.
        {
            const float* fs = Fb + (size_t)(ks * 32 + fchunk * 8) * L + gl0;
            short8 v;
#pragma unroll
            for (int j = 0; j < 8; ++j)
                v[j] = pin ? f2bf(fs[(size_t)j * L]) : (short)0;
            *(short8*)fdst = v;
        }
        __syncthreads();
        short8 bfrag = *(const short8*)(Ft + wav * 512 + lane * 8);
#pragma unroll
        for (int mt = 0; mt < 16; ++mt) {
            short8 afrag = *(const short8*)(Wt + mt * 512 + lane * 8);
            acc[mt] = __builtin_amdgcn_mfma_f32_16x16x32_bf16(afrag, bfrag, acc[mt], 0, 0, 0);
        }
    }

    // Epilogue. C/D layout (validated): col(pixel)=lane&15, row(channel)=quad*4+reg.
    float ss = 0.f;
#pragma unroll
    for (int mt = 0; mt < 16; ++mt) {
        float4_ bv = *(const float4_*)(bias + mt * 16 + quad * 4);
#pragma unroll
        for (int r = 0; r < 4; ++r) {
            float v = acc[mt][r] + bv[r];
            acc[mt][r] = v;
            ss += v * v;
        }
    }
    ss += __shfl_xor(ss, 16);
    ss += __shfl_xor(ss, 32);
    const float inv = 1.f / sqrtf(fmaxf(ss, 1e-24f));

    // Two-pass transpose (32 px per pass) through Ut (aliases Wt/Ft behind barriers).
    const int pxl = wav * 16 + ln;
#pragma unroll
    for (int p = 0; p < 2; ++p) {
        __syncthreads();
        if ((pxl >> 5) == p) {
#pragma unroll
            for (int mt = 0; mt < 16; ++mt) {
                short4_ v;
#pragma unroll
                for (int r = 0; r < 4; ++r) v[r] = f2bf(acc[mt][r] * inv);
                *(short4_*)(&Ut[(pxl & 31) * TPITCH + mt * 16 + quad * 4]) = v;
            }
        }
        __syncthreads();
        const int opx = t >> 3;            // 0..31
        const int c0 = (t & 7) * 32;       // 32 ch per thread
        const int gpx = pixbase + p * 32 + opx;
        if (gpx < L) {
            short* dst = U + ((size_t)b * L + gpx) * CCH + c0;
#pragma unroll
            for (int k = 0; k < 4; ++k)
                *(short8*)(dst + k * 8) = *(const short8*)(&Ut[opx * TPITCH + c0 + k * 8]);
        }
    }
}

// ---------- cell_dots: all six pair sums, single-touch reads ----------
// Block = one (b, scale-3 cell). Thread (c1 = t>>4: 4x4 scale-1 subcell, k = t&15:
// 16-ch chunk). Reads: 4 u0 px per thread (the c1 subcell's 2x2), u1[c1], u2[parent],
// u3[cell]. Computes d01,d02,d03 (per u0 px), d12,d13 (per u1 px), d23 (per u2 px,
// deduped to one thread per u2 cell).
__global__ __launch_bounds__(256) void cell_dots(
    const short* __restrict__ u0, const short* __restrict__ u1,
    const short* __restrict__ u2, const short* __restrict__ u3,
    float* __restrict__ sums) {
    const int b  = blockIdx.y;
    const int c3 = blockIdx.x;               // 0..99
    const int H3 = c3 / 10, W3 = c3 - H3 * 10;
    const int t  = threadIdx.x;
    const int c1 = t >> 4;
    const int k  = t & 15;
    const int h1 = c1 >> 2, w1 = c1 & 3;
    const int r1 = 4 * H3 + h1, q1 = 4 * W3 + w1;
    const int px1 = r1 * 40 + q1;
    const int px2 = (2 * H3 + (h1 >> 1)) * 20 + (2 * W3 + (w1 >> 1));
    const int px3 = H3 * 10 + W3;

    float b1v[16], b2v[16], b3v[16];
    {
        const short* p1 = u1 + ((size_t)(b * 1600 + px1)) * CCH + k * 16;
        const short* p2 = u2 + ((size_t)(b * 400  + px2)) * CCH + k * 16;
        const short* p3 = u3 + ((size_t)(b * 100  + px3)) * CCH + k * 16;
#pragma unroll
        for (int h = 0; h < 2; ++h) {
            short8 v1 = *(const short8*)(p1 + h * 8);
            short8 v2 = *(const short8*)(p2 + h * 8);
            short8 v3 = *(const short8*)(p3 + h * 8);
#pragma unroll
            for (int e = 0; e < 8; ++e) {
                b1v[h * 8 + e] = bf2f(v1[e]);
                b2v[h * 8 + e] = bf2f(v2[e]);
                b3v[h * 8 + e] = bf2f(v3[e]);
            }
        }
    }

    float d01 = 0.f, d02 = 0.f, d03 = 0.f;
#pragma unroll
    for (int dh = 0; dh < 2; ++dh) {
#pragma unroll
        for (int dw = 0; dw < 2; ++dw) {
            const int px0 = (2 * r1 + dh) * 80 + 2 * q1 + dw;
            const short* pa = u0 + ((size_t)(b * 6400 + px0)) * CCH + k * 16;
            float av[16];
#pragma unroll
            for (int h = 0; h < 2; ++h) {
                short8 v = *(const short8*)(pa + h * 8);
#pragma unroll
                for (int e = 0; e < 8; ++e) av[h * 8 + e] = bf2f(v[e]);
            }
#pragma unroll
            for (int e = 0; e < 16; ++e) {
                d01 += av[e] * b1v[e];
                d02 += av[e] * b2v[e];
                d03 += av[e] * b3v[e];
            }
        }
    }
    float d12 = 0.f, d13 = 0.f, d23 = 0.f;
#pragma unroll
    for (int e = 0; e < 16; ++e) {
        d12 += b1v[e] * b2v[e];
        d13 += b1v[e] * b3v[e];
    }
    if (((h1 & 1) | (w1 & 1)) == 0) {
#pragma unroll
        for (int e = 0; e < 16; ++e) d23 += b2v[e] * b3v[e];
    }

    // Block reduction of the 6 sums, then one atomic each.
    float vals[6] = {d01, d02, d03, d12, d13, d23};
    __shared__ float red[4][6];
    const int lane = t & 63, wav = t >> 6;
#pragma unroll
    for (int p = 0; p < 6; ++p) {
        float v = vals[p];
        v += __shfl_xor(v, 1);  v += __shfl_xor(v, 2);  v += __shfl_xor(v, 4);
        v += __shfl_xor(v, 8);  v += __shfl_xor(v, 16); v += __shfl_xor(v, 32);
        if (lane == 0) red[wav][p] = v;
    }
    __syncthreads();
    if (t < 6)
        atomicAdd(&sums[b * 6 + t], red[0][t] + red[1][t] + red[2][t] + red[3][t]);
}

// ---------- Softmax over j for each (b,i) row ----------
__global__ void softmax4(const float* __restrict__ sums, float* __restrict__ out) {
    int t = threadIdx.x;
    if (t >= 128) return;
    int b = t >> 4, i = (t >> 2) & 3, j = t & 3;
    float a[4];
#pragma unroll
    for (int jj = 0; jj < 4; ++jj) {
        if (jj == i) { a[jj] = 1.0f; continue; }
        int lo = i < jj ? i : jj;
        int hi = i < jj ? jj : i;
        int pidx;
        if (lo == 0) pidx = hi - 1;          // (0,1)=0 (0,2)=1 (0,3)=2
        else if (lo == 1) pidx = 1 + hi;     // (1,2)=3 (1,3)=4
        else pidx = 5;                       // (2,3)=5
        int rf = 80 >> lo;
        a[jj] = sums[b * 6 + pidx] / (float)(rf * rf);
    }
    float m = fmaxf(fmaxf(a[0], a[1]), fmaxf(a[2], a[3]));
    float e0 = expf(a[0] - m), e1 = expf(a[1] - m), e2 = expf(a[2] - m), e3 = expf(a[3] - m);
    float sum = e0 + e1 + e2 + e3;
    float ev = (j == 0) ? e0 : (j == 1) ? e1 : (j == 2) ? e2 : e3;
    out[t] = ev / sum;
}

extern "C" void kernel_launch(void* const* d_in, const int* in_sizes, int n_in,
                              void* d_out, int out_size, void* d_ws, size_t ws_size,
                              hipStream_t stream) {
    // setup_inputs dict insertion order: f0,w0,b0, f1,w1,b1, f2,w2,b2, f3,w3,b3
    const float* f[4]  = {(const float*)d_in[0], (const float*)d_in[3],
                          (const float*)d_in[6], (const float*)d_in[9]};
    const float* w[4]  = {(const float*)d_in[1], (const float*)d_in[4],
                          (const float*)d_in[7], (const float*)d_in[10]};
    const float* bs[4] = {(const float*)d_in[2], (const float*)d_in[5],
                          (const float*)d_in[8], (const float*)d_in[11]};

    const int Ls[4] = {6400, 1600, 400, 100};
    char* ws = (char*)d_ws;
    size_t off = 0;
    short* u[4];
    for (int s = 0; s < 4; ++s) {
        u[s] = (short*)(ws + off);
        off += (size_t)8 * CCH * Ls[s] * sizeof(short);
    }
    short* wp = (short*)(ws + off); off += 4 * 65536 * sizeof(short);
    float* sums = (float*)(ws + off);   // 48 floats

    hipMemsetAsync(sums, 0, 64 * sizeof(float), stream);

    pack_w<<<dim3(32, 4), 256, 0, stream>>>(w[0], w[1], w[2], w[3], wp);

    proj_norm<<<1072, 256, 0, stream>>>(f[0], f[1], f[2], f[3], wp,
                                        bs[0], bs[1], bs[2], bs[3],
                                        u[0], u[1], u[2], u[3]);

    cell_dots<<<dim3(100, 8), 256, 0, stream>>>(u[0], u[1], u[2], u[3], sums);

    softmax4<<<1, 128, 0, stream>>>(sums, (float*)d_out);
}

// Round 7
// 168.845 us; speedup vs baseline: 1.4420x; 1.4420x over previous
//
#include <hip/hip_runtime.h>

// EdgeAttention: 4-scale 1x1-conv projection + pairwise per-pixel cosine + 4x4 softmax.
// Round 7:
//  - 3 kernel nodes (was 5): pack_w folded into proj (direct fp32->bf16 LDS staging of
//    the L2-resident 1MB W), memset dropped (cell_dots writes unique partial slots).
//  - proj: register-prefetch pipeline — global W+F loads for iter ks+1 issued after the
//    second barrier so their latency overlaps the ds_read/MFMA phase (proj was shown
//    latency-bound: r6 Occupancy 15% with everything idle).
//  - epilogue: direct pixel-major short4 stores (no LDS transpose/alias).
//  - pair pass: r6 cell_dots (validated, single-touch) -> partial slots, no atomics.
// Nearest upsample == block replication (src = dst >> d). Diagonal attn == 1 exactly.

#define CCH 256
#define WPITCH 40   // shorts per 32-ch fragment row (64 B data + 16 B pad)

typedef __attribute__((ext_vector_type(8))) short short8;
typedef __attribute__((ext_vector_type(4))) short short4_;
typedef __attribute__((ext_vector_type(4))) float float4_;

__device__ inline short f2bf(float x) {   // round-to-nearest-even fp32 -> bf16
    union { float f; unsigned u; } c; c.f = x;
    unsigned u = c.u + 0x7FFFu + ((c.u >> 16) & 1u);
    return (short)(u >> 16);
}
__device__ inline float bf2f(short b) {
    union { unsigned u; float f; } c; c.u = ((unsigned)(unsigned short)b) << 16;
    return c.f;
}

// ---------- Projection GEMM (bf16 MFMA, LDS-staged, reg-prefetch) ----------
// 256 thr = 4 waves; block computes 256 out-ch for 64 pixels of one (scale,b).
// LDS rows are MFMA fragment rows: [row][kk0..kk31] pitch WPITCH; frag read at
// row*WPITCH + quad*8 (2-way bank alias only).
__global__ __launch_bounds__(256) void proj_norm(
    const float* __restrict__ f0, const float* __restrict__ f1,
    const float* __restrict__ f2, const float* __restrict__ f3,
    const float* __restrict__ w0, const float* __restrict__ w1,
    const float* __restrict__ w2, const float* __restrict__ w3,
    const float* __restrict__ b0, const float* __restrict__ b1,
    const float* __restrict__ b2, const float* __restrict__ b3,
    short* __restrict__ u0, short* __restrict__ u1,
    short* __restrict__ u2, short* __restrict__ u3)
{
    __shared__ __align__(16) short Wt[256 * WPITCH];   // 20480 B
    __shared__ __align__(16) short Ft[64 * WPITCH];    //  5120 B

    const int blk = blockIdx.x;
    int s, b, tile, L;
    const float* F; const float* Wg; const float* bias; short* U;
    if (blk < 800)       { s = 0; int r = blk;        b = r / 100; tile = r % 100; L = 6400; F = f0; Wg = w0; bias = b0; U = u0; }
    else if (blk < 1000) { s = 1; int r = blk - 800;  b = r / 25;  tile = r % 25;  L = 1600; F = f1; Wg = w1; bias = b1; U = u1; }
    else if (blk < 1056) { s = 2; int r = blk - 1000; b = r / 7;   tile = r % 7;   L = 400;  F = f2; Wg = w2; bias = b2; U = u2; }
    else                 { s = 3; int r = blk - 1056; b = r / 2;   tile = r % 2;   L = 100;  F = f3; Wg = w3; bias = b3; U = u3; }

    const int t    = threadIdx.x;
    const int lane = t & 63;
    const int wav  = t >> 6;
    const int ln   = lane & 15;
    const int quad = lane >> 4;
    const int pixbase = tile * 64;
    const float* Fb = F + (size_t)b * CCH * L;

    // W staging assignment: thread covers (o = p*64 + wo, ch kk = wk..wk+7), p = 0..3.
    const int wo = t >> 2;          // 0..63
    const int wk = (t & 3) * 8;     // 0,8,16,24
    // F staging assignment: thread covers (pixel fpix, ch fchunk*8..+7).
    const int fpix = t & 63;
    const int fchunk = t >> 6;
    const int gpix0 = pixbase + fpix;
    const bool pin = gpix0 < L;
    const int gl0 = pin ? gpix0 : 0;

    float4_ wbufA[4], wbufB[4];
    float fbuf[8];

    auto loadW = [&](int ks) {
#pragma unroll
        for (int p = 0; p < 4; ++p) {
            const float* srcp = Wg + (size_t)(p * 64 + wo) * CCH + ks * 32 + wk;
            wbufA[p] = *(const float4_*)srcp;
            wbufB[p] = *(const float4_*)(srcp + 4);
        }
    };
    auto loadF = [&](int ks) {
        const float* fs = Fb + (size_t)(ks * 32 + fchunk * 8) * L + gl0;
#pragma unroll
        for (int j = 0; j < 8; ++j) fbuf[j] = fs[(size_t)j * L];
    };

    float4_ acc[16];
#pragma unroll
    for (int i = 0; i < 16; ++i) acc[i] = (float4_){0.f, 0.f, 0.f, 0.f};

    loadW(0);
    loadF(0);

    for (int ks = 0; ks < 8; ++ks) {
        __syncthreads();
        // Stage prefetched registers -> LDS (fp32 -> bf16 convert here).
#pragma unroll
        for (int p = 0; p < 4; ++p) {
            short8 v;
#pragma unroll
            for (int e = 0; e < 4; ++e) {
                v[e]     = f2bf(wbufA[p][e]);
                v[e + 4] = f2bf(wbufB[p][e]);
            }
            *(short8*)(&Wt[(p * 64 + wo) * WPITCH + wk]) = v;
        }
        {
            short8 v;
#pragma unroll
            for (int j = 0; j < 8; ++j) v[j] = pin ? f2bf(fbuf[j]) : (short)0;
            *(short8*)(&Ft[fpix * WPITCH + fchunk * 8]) = v;
        }
        __syncthreads();
        // Issue next iteration's global loads; their latency overlaps the MFMA phase
        // (vmcnt drain happens at the next top-of-loop barrier).
        const int ksn = (ks + 1) & 7;
        loadW(ksn);
        loadF(ksn);

        short8 bfrag = *(const short8*)(&Ft[(wav * 16 + ln) * WPITCH + quad * 8]);
#pragma unroll
        for (int mt = 0; mt < 16; ++mt) {
            short8 afrag = *(const short8*)(&Wt[(mt * 16 + ln) * WPITCH + quad * 8]);
            acc[mt] = __builtin_amdgcn_mfma_f32_16x16x32_bf16(afrag, bfrag, acc[mt], 0, 0, 0);
        }
    }

    // Epilogue. C/D layout (validated): col(pixel)=lane&15, row(channel)=quad*4+reg.
    float ss = 0.f;
#pragma unroll
    for (int mt = 0; mt < 16; ++mt) {
        float4_ bv = *(const float4_*)(bias + mt * 16 + quad * 4);
#pragma unroll
        for (int r = 0; r < 4; ++r) {
            float v = acc[mt][r] + bv[r];
            acc[mt][r] = v;
            ss += v * v;
        }
    }
    ss += __shfl_xor(ss, 16);
    ss += __shfl_xor(ss, 32);
    const float inv = 1.f / sqrtf(fmaxf(ss, 1e-24f));

    // Direct pixel-major store: u[b][px][ch] bf16, short4 per mt (8 B).
    const int gpixw = pixbase + wav * 16 + ln;
    if (gpixw < L) {
        short* dst = U + ((size_t)b * L + gpixw) * CCH;
#pragma unroll
        for (int mt = 0; mt < 16; ++mt) {
            short4_ v;
#pragma unroll
            for (int r = 0; r < 4; ++r) v[r] = f2bf(acc[mt][r] * inv);
            *(short4_*)(dst + mt * 16 + quad * 4) = v;
        }
    }
}

// ---------- cell_dots: all six pair sums, single-touch reads ----------
// Block = one (b, scale-3 cell). Thread (c1 = t>>4: 4x4 scale-1 subcell, k = t&15:
// 16-ch chunk). Writes its block's 6 partials to unique slots (no memset/atomics).
__global__ __launch_bounds__(256) void cell_dots(
    const short* __restrict__ u0, const short* __restrict__ u1,
    const short* __restrict__ u2, const short* __restrict__ u3,
    float* __restrict__ partial) {
    const int b  = blockIdx.y;
    const int c3 = blockIdx.x;               // 0..99
    const int H3 = c3 / 10, W3 = c3 - H3 * 10;
    const int t  = threadIdx.x;
    const int c1 = t >> 4;
    const int k  = t & 15;
    const int h1 = c1 >> 2, w1 = c1 & 3;
    const int r1 = 4 * H3 + h1, q1 = 4 * W3 + w1;
    const int px1 = r1 * 40 + q1;
    const int px2 = (2 * H3 + (h1 >> 1)) * 20 + (2 * W3 + (w1 >> 1));
    const int px3 = H3 * 10 + W3;

    float b1v[16], b2v[16], b3v[16];
    {
        const short* p1 = u1 + ((size_t)(b * 1600 + px1)) * CCH + k * 16;
        const short* p2 = u2 + ((size_t)(b * 400  + px2)) * CCH + k * 16;
        const short* p3 = u3 + ((size_t)(b * 100  + px3)) * CCH + k * 16;
#pragma unroll
        for (int h = 0; h < 2; ++h) {
            short8 v1 = *(const short8*)(p1 + h * 8);
            short8 v2 = *(const short8*)(p2 + h * 8);
            short8 v3 = *(const short8*)(p3 + h * 8);
#pragma unroll
            for (int e = 0; e < 8; ++e) {
                b1v[h * 8 + e] = bf2f(v1[e]);
                b2v[h * 8 + e] = bf2f(v2[e]);
                b3v[h * 8 + e] = bf2f(v3[e]);
            }
        }
    }

    float d01 = 0.f, d02 = 0.f, d03 = 0.f;
#pragma unroll
    for (int dh = 0; dh < 2; ++dh) {
#pragma unroll
        for (int dw = 0; dw < 2; ++dw) {
            const int px0 = (2 * r1 + dh) * 80 + 2 * q1 + dw;
            const short* pa = u0 + ((size_t)(b * 6400 + px0)) * CCH + k * 16;
            float av[16];
#pragma unroll
            for (int h = 0; h < 2; ++h) {
                short8 v = *(const short8*)(pa + h * 8);
#pragma unroll
                for (int e = 0; e < 8; ++e) av[h * 8 + e] = bf2f(v[e]);
            }
#pragma unroll
            for (int e = 0; e < 16; ++e) {
                d01 += av[e] * b1v[e];
                d02 += av[e] * b2v[e];
                d03 += av[e] * b3v[e];
            }
        }
    }
    float d12 = 0.f, d13 = 0.f, d23 = 0.f;
#pragma unroll
    for (int e = 0; e < 16; ++e) {
        d12 += b1v[e] * b2v[e];
        d13 += b1v[e] * b3v[e];
    }
    if (((h1 & 1) | (w1 & 1)) == 0) {
#pragma unroll
        for (int e = 0; e < 16; ++e) d23 += b2v[e] * b3v[e];
    }

    float vals[6] = {d01, d02, d03, d12, d13, d23};
    __shared__ float red[4][6];
    const int lane = t & 63, wav = t >> 6;
#pragma unroll
    for (int p = 0; p < 6; ++p) {
        float v = vals[p];
        v += __shfl_xor(v, 1);  v += __shfl_xor(v, 2);  v += __shfl_xor(v, 4);
        v += __shfl_xor(v, 8);  v += __shfl_xor(v, 16); v += __shfl_xor(v, 32);
        if (lane == 0) red[wav][p] = v;
    }
    __syncthreads();
    if (t < 6)
        partial[((size_t)b * 6 + t) * 100 + c3] =
            red[0][t] + red[1][t] + red[2][t] + red[3][t];
}

// ---------- Softmax over j for each (b,i) row (sums cell partials) ----------
__global__ void softmax4(const float* __restrict__ partial, float* __restrict__ out) {
    int t = threadIdx.x;
    if (t >= 128) return;
    int b = t >> 4, i = (t >> 2) & 3, j = t & 3;
    float a[4];
#pragma unroll
    for (int jj = 0; jj < 4; ++jj) {
        if (jj == i) { a[jj] = 1.0f; continue; }
        int lo = i < jj ? i : jj;
        int hi = i < jj ? jj : i;
        int pidx;
        if (lo == 0) pidx = hi - 1;          // (0,1)=0 (0,2)=1 (0,3)=2
        else if (lo == 1) pidx = 1 + hi;     // (1,2)=3 (1,3)=4
        else pidx = 5;                       // (2,3)=5
        const float* pp = partial + ((size_t)b * 6 + pidx) * 100;
        float s = 0.f;
        for (int k = 0; k < 100; ++k) s += pp[k];
        int rf = 80 >> lo;
        a[jj] = s / (float)(rf * rf);
    }
    float m = fmaxf(fmaxf(a[0], a[1]), fmaxf(a[2], a[3]));
    float e0 = expf(a[0] - m), e1 = expf(a[1] - m), e2 = expf(a[2] - m), e3 = expf(a[3] - m);
    float sum = e0 + e1 + e2 + e3;
    float ev = (j == 0) ? e0 : (j == 1) ? e1 : (j == 2) ? e2 : e3;
    out[t] = ev / sum;
}

extern "C" void kernel_launch(void* const* d_in, const int* in_sizes, int n_in,
                              void* d_out, int out_size, void* d_ws, size_t ws_size,
                              hipStream_t stream) {
    // setup_inputs dict insertion order: f0,w0,b0, f1,w1,b1, f2,w2,b2, f3,w3,b3
    const float* f[4]  = {(const float*)d_in[0], (const float*)d_in[3],
                          (const float*)d_in[6], (const float*)d_in[9]};
    const float* w[4]  = {(const float*)d_in[1], (const float*)d_in[4],
                          (const float*)d_in[7], (const float*)d_in[10]};
    const float* bs[4] = {(const float*)d_in[2], (const float*)d_in[5],
                          (const float*)d_in[8], (const float*)d_in[11]};

    const int Ls[4] = {6400, 1600, 400, 100};
    char* ws = (char*)d_ws;
    size_t off = 0;
    short* u[4];
    for (int s = 0; s < 4; ++s) {
        u[s] = (short*)(ws + off);
        off += (size_t)8 * CCH * Ls[s] * sizeof(short);
    }
    float* partial = (float*)(ws + off);   // 8*6*100 floats

    proj_norm<<<1072, 256, 0, stream>>>(f[0], f[1], f[2], f[3],
                                        w[0], w[1], w[2], w[3],
                                        bs[0], bs[1], bs[2], bs[3],
                                        u[0], u[1], u[2], u[3]);

    cell_dots<<<dim3(100, 8), 256, 0, stream>>>(u[0], u[1], u[2], u[3], partial);

    softmax4<<<1, 128, 0, stream>>>(partial, (float*)d_out);
}

// Round 8
// 167.718 us; speedup vs baseline: 1.4517x; 1.0067x over previous
//
#include <hip/hip_runtime.h>

// EdgeAttention: 4-scale 1x1-conv projection + pairwise per-pixel cosine + 4x4 softmax.
// Round 8: eliminate u0 (26 MB write + 26 MB read) by fusing scale-0 projection with the
// pair-dot accumulation. Blocks of the fused kernel ARE the scale-3 cells: each computes
// the 1x1-conv for its 8x8 scale-0 patch (r7's MFMA K-loop, F remapped to cell geometry),
// normalizes in-register, stages the cell's 21 coarse unit vectors (u1:16, u2:4, u3:1 =
// 10.5 KB) into LDS, and accumulates all six pair dot sums. proj_small precomputes
// u1/u2/u3 (272 blocks, r7 structure). Nearest upsample == block replication. Diagonal
// attn == 1 exactly.

#define CCH 256
#define WPITCH 40   // shorts per 32-ch fragment row (64 B data + 16 B pad)

typedef __attribute__((ext_vector_type(8))) short short8;
typedef __attribute__((ext_vector_type(4))) short short4_;
typedef __attribute__((ext_vector_type(4))) float float4_;

__device__ inline short f2bf(float x) {   // round-to-nearest-even fp32 -> bf16
    union { float f; unsigned u; } c; c.f = x;
    unsigned u = c.u + 0x7FFFu + ((c.u >> 16) & 1u);
    return (short)(u >> 16);
}
__device__ inline float bf2f(short b) {
    union { unsigned u; float f; } c; c.u = ((unsigned)(unsigned short)b) << 16;
    return c.f;
}

// ---------- proj_small: scales 1..3 -> pixel-major unit vectors (r7 structure) ----------
__global__ __launch_bounds__(256) void proj_small(
    const float* __restrict__ f1, const float* __restrict__ f2,
    const float* __restrict__ f3,
    const float* __restrict__ w1, const float* __restrict__ w2,
    const float* __restrict__ w3,
    const float* __restrict__ b1, const float* __restrict__ b2,
    const float* __restrict__ b3,
    short* __restrict__ u1, short* __restrict__ u2, short* __restrict__ u3)
{
    __shared__ __align__(16) short Wt[256 * WPITCH];
    __shared__ __align__(16) short Ft[64 * WPITCH];

    const int blk = blockIdx.x;
    int b, tile, L;
    const float* F; const float* Wg; const float* bias; short* U;
    if (blk < 200)      { int r = blk;       b = r / 25; tile = r % 25; L = 1600; F = f1; Wg = w1; bias = b1; U = u1; }
    else if (blk < 256) { int r = blk - 200; b = r / 7;  tile = r % 7;  L = 400;  F = f2; Wg = w2; bias = b2; U = u2; }
    else                { int r = blk - 256; b = r / 2;  tile = r % 2;  L = 100;  F = f3; Wg = w3; bias = b3; U = u3; }

    const int t    = threadIdx.x;
    const int lane = t & 63;
    const int wav  = t >> 6;
    const int ln   = lane & 15;
    const int quad = lane >> 4;
    const int pixbase = tile * 64;
    const float* Fb = F + (size_t)b * CCH * L;

    const int wo = t >> 2;
    const int wk = (t & 3) * 8;
    const int fpix = t & 63;
    const int fchunk = t >> 6;
    const int gpix0 = pixbase + fpix;
    const bool pin = gpix0 < L;
    const int gl0 = pin ? gpix0 : 0;

    float4_ wbufA[4], wbufB[4];
    float fbuf[8];
    auto loadW = [&](int ks) {
#pragma unroll
        for (int p = 0; p < 4; ++p) {
            const float* srcp = Wg + (size_t)(p * 64 + wo) * CCH + ks * 32 + wk;
            wbufA[p] = *(const float4_*)srcp;
            wbufB[p] = *(const float4_*)(srcp + 4);
        }
    };
    auto loadF = [&](int ks) {
        const float* fs = Fb + (size_t)(ks * 32 + fchunk * 8) * L + gl0;
#pragma unroll
        for (int j = 0; j < 8; ++j) fbuf[j] = fs[(size_t)j * L];
    };

    float4_ acc[16];
#pragma unroll
    for (int i = 0; i < 16; ++i) acc[i] = (float4_){0.f, 0.f, 0.f, 0.f};

    loadW(0); loadF(0);
    for (int ks = 0; ks < 8; ++ks) {
        __syncthreads();
#pragma unroll
        for (int p = 0; p < 4; ++p) {
            short8 v;
#pragma unroll
            for (int e = 0; e < 4; ++e) { v[e] = f2bf(wbufA[p][e]); v[e + 4] = f2bf(wbufB[p][e]); }
            *(short8*)(&Wt[(p * 64 + wo) * WPITCH + wk]) = v;
        }
        {
            short8 v;
#pragma unroll
            for (int j = 0; j < 8; ++j) v[j] = pin ? f2bf(fbuf[j]) : (short)0;
            *(short8*)(&Ft[fpix * WPITCH + fchunk * 8]) = v;
        }
        __syncthreads();
        const int ksn = (ks + 1) & 7;
        loadW(ksn); loadF(ksn);

        short8 bfrag = *(const short8*)(&Ft[(wav * 16 + ln) * WPITCH + quad * 8]);
#pragma unroll
        for (int mt = 0; mt < 16; ++mt) {
            short8 afrag = *(const short8*)(&Wt[(mt * 16 + ln) * WPITCH + quad * 8]);
            acc[mt] = __builtin_amdgcn_mfma_f32_16x16x32_bf16(afrag, bfrag, acc[mt], 0, 0, 0);
        }
    }

    float ss = 0.f;
#pragma unroll
    for (int mt = 0; mt < 16; ++mt) {
        float4_ bv = *(const float4_*)(bias + mt * 16 + quad * 4);
#pragma unroll
        for (int r = 0; r < 4; ++r) { float v = acc[mt][r] + bv[r]; acc[mt][r] = v; ss += v * v; }
    }
    ss += __shfl_xor(ss, 16);
    ss += __shfl_xor(ss, 32);
    const float inv = 1.f / sqrtf(fmaxf(ss, 1e-24f));

    const int gpixw = pixbase + wav * 16 + ln;
    if (gpixw < L) {
        short* dst = U + ((size_t)b * L + gpixw) * CCH;
#pragma unroll
        for (int mt = 0; mt < 16; ++mt) {
            short4_ v;
#pragma unroll
            for (int r = 0; r < 4; ++r) v[r] = f2bf(acc[mt][r] * inv);
            *(short4_*)(dst + mt * 16 + quad * 4) = v;
        }
    }
}

// ---------- proj0_dots: scale-0 projection fused with all six pair dot sums ----------
// Block = (b, scale-3 cell c3). Pixels: local p = ph*8+pw -> global (8H3+ph, 8W3+pw).
__global__ __launch_bounds__(256) void proj0_dots(
    const float* __restrict__ F, const float* __restrict__ Wg,
    const float* __restrict__ bias,
    const short* __restrict__ u1, const short* __restrict__ u2,
    const short* __restrict__ u3,
    float* __restrict__ partial)
{
    __shared__ __align__(16) short Wt[256 * WPITCH];   // 20480 B
    __shared__ __align__(16) short Ft[64 * WPITCH];    //  5120 B
    short* S1 = Wt;            // epilogue alias: 16*256 shorts (8192 B)
    short* S2 = Wt + 4096;     // 4*256 shorts (2048 B)
    short* S3 = Wt + 5120;     // 256 shorts (512 B); total 10752 B < 20480
    __shared__ float red[4][3];
    __shared__ float redB[3];

    const int c3 = blockIdx.x;   // 0..99
    const int b  = blockIdx.y;
    const int H3 = c3 / 10, W3 = c3 - H3 * 10;

    const int t    = threadIdx.x;
    const int lane = t & 63;
    const int wav  = t >> 6;
    const int ln   = lane & 15;
    const int quad = lane >> 4;
    const float* Fb = F + (size_t)b * CCH * 6400;

    const int wo = t >> 2;
    const int wk = (t & 3) * 8;
    const int fpix = t & 63;
    const int fchunk = t >> 6;
    const int gl = (8 * H3 + (fpix >> 3)) * 80 + 8 * W3 + (fpix & 7);

    float4_ wbufA[4], wbufB[4];
    float fbuf[8];
    auto loadW = [&](int ks) {
#pragma unroll
        for (int p = 0; p < 4; ++p) {
            const float* srcp = Wg + (size_t)(p * 64 + wo) * CCH + ks * 32 + wk;
            wbufA[p] = *(const float4_*)srcp;
            wbufB[p] = *(const float4_*)(srcp + 4);
        }
    };
    auto loadF = [&](int ks) {
        const float* fs = Fb + (size_t)(ks * 32 + fchunk * 8) * 6400 + gl;
#pragma unroll
        for (int j = 0; j < 8; ++j) fbuf[j] = fs[(size_t)j * 6400];
    };

    float4_ acc[16];
#pragma unroll
    for (int i = 0; i < 16; ++i) acc[i] = (float4_){0.f, 0.f, 0.f, 0.f};

    loadW(0); loadF(0);
    for (int ks = 0; ks < 8; ++ks) {
        __syncthreads();
#pragma unroll
        for (int p = 0; p < 4; ++p) {
            short8 v;
#pragma unroll
            for (int e = 0; e < 4; ++e) { v[e] = f2bf(wbufA[p][e]); v[e + 4] = f2bf(wbufB[p][e]); }
            *(short8*)(&Wt[(p * 64 + wo) * WPITCH + wk]) = v;
        }
        {
            short8 v;
#pragma unroll
            for (int j = 0; j < 8; ++j) v[j] = f2bf(fbuf[j]);
            *(short8*)(&Ft[fpix * WPITCH + fchunk * 8]) = v;
        }
        __syncthreads();
        const int ksn = (ks + 1) & 7;
        loadW(ksn); loadF(ksn);

        short8 bfrag = *(const short8*)(&Ft[(wav * 16 + ln) * WPITCH + quad * 8]);
#pragma unroll
        for (int mt = 0; mt < 16; ++mt) {
            short8 afrag = *(const short8*)(&Wt[(mt * 16 + ln) * WPITCH + quad * 8]);
            acc[mt] = __builtin_amdgcn_mfma_f32_16x16x32_bf16(afrag, bfrag, acc[mt], 0, 0, 0);
        }
    }

    // Bias + per-pixel norm. C/D layout (validated): col(pixel)=lane&15, row(ch)=quad*4+r.
    float ss = 0.f;
#pragma unroll
    for (int mt = 0; mt < 16; ++mt) {
        float4_ bv = *(const float4_*)(bias + mt * 16 + quad * 4);
#pragma unroll
        for (int r = 0; r < 4; ++r) { float v = acc[mt][r] + bv[r]; acc[mt][r] = v; ss += v * v; }
    }
    ss += __shfl_xor(ss, 16);
    ss += __shfl_xor(ss, 32);
    const float inv = 1.f / sqrtf(fmaxf(ss, 1e-24f));

    __syncthreads();   // S1/S2/S3 alias Wt: all K-loop LDS traffic must be done

    // Stage coarse unit vectors into LDS (coalesced 32-B chunks per thread).
    {
        const int p1 = t >> 4, ck = (t & 15) * 16;
        const int h1 = p1 >> 2, w1 = p1 & 3;
        const short* src = u1 + ((size_t)(b * 1600 + (4 * H3 + h1) * 40 + 4 * W3 + w1)) * CCH + ck;
        *(short8*)(&S1[p1 * 256 + ck])     = *(const short8*)src;
        *(short8*)(&S1[p1 * 256 + ck + 8]) = *(const short8*)(src + 8);
    }
    if (t < 64) {
        const int p2 = t >> 4, ck = (t & 15) * 16;
        const int h2 = p2 >> 1, w2 = p2 & 1;
        const short* src = u2 + ((size_t)(b * 400 + (2 * H3 + h2) * 20 + 2 * W3 + w2)) * CCH + ck;
        *(short8*)(&S2[p2 * 256 + ck])     = *(const short8*)src;
        *(short8*)(&S2[p2 * 256 + ck + 8]) = *(const short8*)(src + 8);
    }
    if (t < 16) {
        const int ck = t * 16;
        const short* src = u3 + ((size_t)(b * 100 + H3 * 10 + W3)) * CCH + ck;
        *(short8*)(&S3[ck])     = *(const short8*)src;
        *(short8*)(&S3[ck + 8]) = *(const short8*)(src + 8);
    }
    __syncthreads();

    // Fine dots: lane's pixel pme = wav*16+ln -> (ph,pw); its 64 channels mt*16+quad*4+r.
    const int pme = wav * 16 + ln;
    const int ph = pme >> 3, pw = pme & 7;
    const int c1 = (ph >> 1) * 4 + (pw >> 1);
    const int c2 = (ph >> 2) * 2 + (pw >> 2);
    float d01 = 0.f, d02 = 0.f, d03 = 0.f;
#pragma unroll
    for (int mt = 0; mt < 16; ++mt) {
        const int ch = mt * 16 + quad * 4;
        short4_ v1 = *(const short4_*)(&S1[c1 * 256 + ch]);
        short4_ v2 = *(const short4_*)(&S2[c2 * 256 + ch]);
        short4_ v3 = *(const short4_*)(&S3[ch]);
#pragma unroll
        for (int r = 0; r < 4; ++r) {
            float a = acc[mt][r] * inv;
            d01 += a * bf2f(v1[r]);
            d02 += a * bf2f(v2[r]);
            d03 += a * bf2f(v3[r]);
        }
    }
    float vals[3] = {d01, d02, d03};
#pragma unroll
    for (int p = 0; p < 3; ++p) {
        float v = vals[p];
        v += __shfl_xor(v, 1);  v += __shfl_xor(v, 2);  v += __shfl_xor(v, 4);
        v += __shfl_xor(v, 8);  v += __shfl_xor(v, 16); v += __shfl_xor(v, 32);
        if (lane == 0) red[wav][p] = v;
    }

    // Coarse dots (wave 0 only): d12/d13 over 16 u1-px, d23 over 4 u2-px.
    if (wav == 0) {
        float e12 = 0.f, e13 = 0.f, e23 = 0.f;
        {
            const int cc1 = lane >> 2, q = lane & 3;
            const int cc2 = ((cc1 >> 2) >> 1) * 2 + ((cc1 & 3) >> 1);
#pragma unroll
            for (int k = 0; k < 16; ++k) {
                short4_ a1 = *(const short4_*)(&S1[cc1 * 256 + q * 64 + k * 4]);
                short4_ a2 = *(const short4_*)(&S2[cc2 * 256 + q * 64 + k * 4]);
                short4_ a3 = *(const short4_*)(&S3[q * 64 + k * 4]);
#pragma unroll
                for (int r = 0; r < 4; ++r) {
                    float x1 = bf2f(a1[r]);
                    e12 += x1 * bf2f(a2[r]);
                    e13 += x1 * bf2f(a3[r]);
                }
            }
        }
        if (lane < 16) {
            const int dc2 = lane >> 2, dq = lane & 3;
#pragma unroll
            for (int k = 0; k < 16; ++k) {
                short4_ a2 = *(const short4_*)(&S2[dc2 * 256 + dq * 64 + k * 4]);
                short4_ a3 = *(const short4_*)(&S3[dq * 64 + k * 4]);
#pragma unroll
                for (int r = 0; r < 4; ++r) e23 += bf2f(a2[r]) * bf2f(a3[r]);
            }
        }
        float evals[3] = {e12, e13, e23};
#pragma unroll
        for (int p = 0; p < 3; ++p) {
            float v = evals[p];
            v += __shfl_xor(v, 1);  v += __shfl_xor(v, 2);  v += __shfl_xor(v, 4);
            v += __shfl_xor(v, 8);  v += __shfl_xor(v, 16); v += __shfl_xor(v, 32);
            if (lane == 0) redB[p] = v;
        }
    }
    __syncthreads();
    // partial slots: 0=(0,1) 1=(0,2) 2=(0,3) 3=(1,2) 4=(1,3) 5=(2,3)
    if (t < 3)
        partial[((size_t)b * 6 + t) * 100 + c3] = red[0][t] + red[1][t] + red[2][t] + red[3][t];
    else if (t < 6)
        partial[((size_t)b * 6 + t) * 100 + c3] = redB[t - 3];
}

// ---------- Softmax over j for each (b,i) row (sums cell partials) ----------
__global__ void softmax4(const float* __restrict__ partial, float* __restrict__ out) {
    int t = threadIdx.x;
    if (t >= 128) return;
    int b = t >> 4, i = (t >> 2) & 3, j = t & 3;
    float a[4];
#pragma unroll
    for (int jj = 0; jj < 4; ++jj) {
        if (jj == i) { a[jj] = 1.0f; continue; }
        int lo = i < jj ? i : jj;
        int hi = i < jj ? jj : i;
        int pidx;
        if (lo == 0) pidx = hi - 1;          // (0,1)=0 (0,2)=1 (0,3)=2
        else if (lo == 1) pidx = 1 + hi;     // (1,2)=3 (1,3)=4
        else pidx = 5;                       // (2,3)=5
        const float* pp = partial + ((size_t)b * 6 + pidx) * 100;
        float s = 0.f;
        for (int k = 0; k < 100; ++k) s += pp[k];
        int rf = 80 >> lo;
        a[jj] = s / (float)(rf * rf);
    }
    float m = fmaxf(fmaxf(a[0], a[1]), fmaxf(a[2], a[3]));
    float e0 = expf(a[0] - m), e1 = expf(a[1] - m), e2 = expf(a[2] - m), e3 = expf(a[3] - m);
    float sum = e0 + e1 + e2 + e3;
    float ev = (j == 0) ? e0 : (j == 1) ? e1 : (j == 2) ? e2 : e3;
    out[t] = ev / sum;
}

extern "C" void kernel_launch(void* const* d_in, const int* in_sizes, int n_in,
                              void* d_out, int out_size, void* d_ws, size_t ws_size,
                              hipStream_t stream) {
    // setup_inputs dict insertion order: f0,w0,b0, f1,w1,b1, f2,w2,b2, f3,w3,b3
    const float* f[4]  = {(const float*)d_in[0], (const float*)d_in[3],
                          (const float*)d_in[6], (const float*)d_in[9]};
    const float* w[4]  = {(const float*)d_in[1], (const float*)d_in[4],
                          (const float*)d_in[7], (const float*)d_in[10]};
    const float* bs[4] = {(const float*)d_in[2], (const float*)d_in[5],
                          (const float*)d_in[8], (const float*)d_in[11]};

    char* ws = (char*)d_ws;
    size_t off = 0;
    short* u1 = (short*)(ws + off); off += (size_t)8 * CCH * 1600 * sizeof(short);
    short* u2 = (short*)(ws + off); off += (size_t)8 * CCH * 400  * sizeof(short);
    short* u3 = (short*)(ws + off); off += (size_t)8 * CCH * 100  * sizeof(short);
    float* partial = (float*)(ws + off);   // 8*6*100 floats

    proj_small<<<272, 256, 0, stream>>>(f[1], f[2], f[3],
                                        w[1], w[2], w[3],
                                        bs[1], bs[2], bs[3],
                                        u1, u2, u3);

    proj0_dots<<<dim3(100, 8), 256, 0, stream>>>(f[0], w[0], bs[0],
                                                 u1, u2, u3, partial);

    softmax4<<<1, 128, 0, stream>>>(partial, (float*)d_out);
}

// Round 9
// 159.260 us; speedup vs baseline: 1.5288x; 1.0531x over previous
//
#include <hip/hip_runtime.h>

// EdgeAttention round 9: restructured K-loop around global_load_lds (async DMA).
//  - proj0_dots: 8x16-px tiles (fully coalesced 64-B F rows), 8 waves/block, W (bf16,
//    fragment-linear pre-pack) + F (fp32) DMA'd straight to LDS double buffers; one
//    barrier per K-iter, DMA for iter ks+1 in flight under compute of iter ks. No VGPR
//    staging round-trip (r3..r8's measured ~16us/block bottleneck).
//  - proj_small: unchanged r8 structure (validated), + 32 extra blocks do the W0 pack.
//  - All six pair sums fused as in r8 (validated): fine dots per px, d12/d13 per u1 px,
//    d23 per u2 px; each coarse px owned by exactly one block under 8x16 geometry.
// Nearest upsample == block replication. Diagonal attn == 1 exactly.

#define CCH 256
#define WPITCH 40   // proj_small LDS pitch (r8, validated)

typedef __attribute__((ext_vector_type(8))) short short8;
typedef __attribute__((ext_vector_type(4))) short short4_;
typedef __attribute__((ext_vector_type(4))) float float4_;

__device__ inline short f2bf(float x) {
    union { float f; unsigned u; } c; c.f = x;
    unsigned u = c.u + 0x7FFFu + ((c.u >> 16) & 1u);
    return (short)(u >> 16);
}
__device__ inline float bf2f(short b) {
    union { unsigned u; float f; } c; c.u = ((unsigned)(unsigned short)b) << 16;
    return c.f;
}

__device__ inline void dma16(const void* g, void* l) {
    __builtin_amdgcn_global_load_lds(
        (const __attribute__((address_space(1))) void*)g,
        (__attribute__((address_space(3))) void*)l, 16, 0, 0);
}

// ---------- proj_small: scales 1..3 -> pixel-major unit vectors (r8, validated) ------
// Blocks 272..303 instead pack W0 fp32 -> bf16 fragment-linear for proj0_dots' DMA.
__global__ __launch_bounds__(256) void proj_small(
    const float* __restrict__ f1, const float* __restrict__ f2,
    const float* __restrict__ f3,
    const float* __restrict__ w0, const float* __restrict__ w1,
    const float* __restrict__ w2, const float* __restrict__ w3,
    const float* __restrict__ b1, const float* __restrict__ b2,
    const float* __restrict__ b3,
    short* __restrict__ u1, short* __restrict__ u2, short* __restrict__ u3,
    short* __restrict__ wp)
{
    __shared__ __align__(16) short Wt[256 * WPITCH];
    __shared__ __align__(16) short Ft[64 * WPITCH];

    const int blk = blockIdx.x;
    const int t = threadIdx.x;

    if (blk >= 272) {   // ---- W0 pack: pos = ks*8192 + mt*512 + (quad*16+ln)*8 + e ----
        int id = (blk - 272) * 256 + t;      // 0..8191 short8s
        int ks = id >> 10;
        int rest = id & 1023;
        int mt = rest >> 6;
        int fl = rest & 63;
        int ln = fl & 15, qd = fl >> 4;
        const float* src = w0 + (size_t)(mt * 16 + ln) * CCH + ks * 32 + qd * 8;
        short8 v;
#pragma unroll
        for (int j = 0; j < 8; ++j) v[j] = f2bf(src[j]);
        *(short8*)(wp + (size_t)id * 8) = v;
        return;
    }

    int b, tile, L;
    const float* F; const float* Wg; const float* bias; short* U;
    if (blk < 200)      { int r = blk;       b = r / 25; tile = r % 25; L = 1600; F = f1; Wg = w1; bias = b1; U = u1; }
    else if (blk < 256) { int r = blk - 200; b = r / 7;  tile = r % 7;  L = 400;  F = f2; Wg = w2; bias = b2; U = u2; }
    else                { int r = blk - 256; b = r / 2;  tile = r % 2;  L = 100;  F = f3; Wg = w3; bias = b3; U = u3; }

    const int lane = t & 63;
    const int wav  = t >> 6;
    const int ln   = lane & 15;
    const int quad = lane >> 4;
    const int pixbase = tile * 64;
    const float* Fb = F + (size_t)b * CCH * L;

    const int wo = t >> 2;
    const int wk = (t & 3) * 8;
    const int fpix = t & 63;
    const int fchunk = t >> 6;
    const int gpix0 = pixbase + fpix;
    const bool pin = gpix0 < L;
    const int gl0 = pin ? gpix0 : 0;

    float4_ wbufA[4], wbufB[4];
    float fbuf[8];
    auto loadW = [&](int ks) {
#pragma unroll
        for (int p = 0; p < 4; ++p) {
            const float* srcp = Wg + (size_t)(p * 64 + wo) * CCH + ks * 32 + wk;
            wbufA[p] = *(const float4_*)srcp;
            wbufB[p] = *(const float4_*)(srcp + 4);
        }
    };
    auto loadF = [&](int ks) {
        const float* fs = Fb + (size_t)(ks * 32 + fchunk * 8) * L + gl0;
#pragma unroll
        for (int j = 0; j < 8; ++j) fbuf[j] = fs[(size_t)j * L];
    };

    float4_ acc[16];
#pragma unroll
    for (int i = 0; i < 16; ++i) acc[i] = (float4_){0.f, 0.f, 0.f, 0.f};

    loadW(0); loadF(0);
    for (int ks = 0; ks < 8; ++ks) {
        __syncthreads();
#pragma unroll
        for (int p = 0; p < 4; ++p) {
            short8 v;
#pragma unroll
            for (int e = 0; e < 4; ++e) { v[e] = f2bf(wbufA[p][e]); v[e + 4] = f2bf(wbufB[p][e]); }
            *(short8*)(&Wt[(p * 64 + wo) * WPITCH + wk]) = v;
        }
        {
            short8 v;
#pragma unroll
            for (int j = 0; j < 8; ++j) v[j] = pin ? f2bf(fbuf[j]) : (short)0;
            *(short8*)(&Ft[fpix * WPITCH + fchunk * 8]) = v;
        }
        __syncthreads();
        const int ksn = (ks + 1) & 7;
        loadW(ksn); loadF(ksn);

        short8 bfrag = *(const short8*)(&Ft[(wav * 16 + ln) * WPITCH + quad * 8]);
#pragma unroll
        for (int mt = 0; mt < 16; ++mt) {
            short8 afrag = *(const short8*)(&Wt[(mt * 16 + ln) * WPITCH + quad * 8]);
            acc[mt] = __builtin_amdgcn_mfma_f32_16x16x32_bf16(afrag, bfrag, acc[mt], 0, 0, 0);
        }
    }

    float ss = 0.f;
#pragma unroll
    for (int mt = 0; mt < 16; ++mt) {
        float4_ bv = *(const float4_*)(bias + mt * 16 + quad * 4);
#pragma unroll
        for (int r = 0; r < 4; ++r) { float v = acc[mt][r] + bv[r]; acc[mt][r] = v; ss += v * v; }
    }
    ss += __shfl_xor(ss, 16);
    ss += __shfl_xor(ss, 32);
    const float inv = 1.f / sqrtf(fmaxf(ss, 1e-24f));

    const int gpixw = pixbase + wav * 16 + ln;
    if (gpixw < L) {
        short* dst = U + ((size_t)b * L + gpixw) * CCH;
#pragma unroll
        for (int mt = 0; mt < 16; ++mt) {
            short4_ v;
#pragma unroll
            for (int r = 0; r < 4; ++r) v[r] = f2bf(acc[mt][r] * inv);
            *(short4_*)(dst + mt * 16 + quad * 4) = v;
        }
    }
}

// ---------- proj0_dots v2: DMA double-buffered K-loop + fused pair dots ----------
// Block = (cell c = blockIdx.x in 0..49, b = blockIdx.y). Tile = fine rows [8R,8R+8),
// cols [16C,16C+16), R = c/5, C = c%5. 8 waves, wave w owns px [w*16, w*16+16).
__global__ __launch_bounds__(512) void proj0_dots(
    const float* __restrict__ F, const short* __restrict__ wp,
    const float* __restrict__ bias,
    const short* __restrict__ u1, const short* __restrict__ u2,
    const short* __restrict__ u3,
    float* __restrict__ partial)
{
    __shared__ __align__(16) char smem[65536];
    short* Wb0 = (short*)smem;                    // 16 KB bf16 W slice, buf 0
    short* Wb1 = (short*)(smem + 16384);          // buf 1
    float* Fb0 = (float*)(smem + 32768);          // 16 KB fp32 F slice [ch][128px], buf 0
    float* Fb1 = (float*)(smem + 49152);          // buf 1
    // Epilogue aliases (used only after post-loop barrier):
    short* S1 = (short*)smem;                     // 32 px * 256 ch = 16384 B
    short* S2 = (short*)(smem + 16384);           //  8 px          =  4096 B
    short* S3 = (short*)(smem + 20480);           //  2 px          =  1024 B
    float* redF = (float*)(smem + 24576);         // [8][3]
    float* redC = (float*)(smem + 24576 + 96);    // [3][2]

    const int c  = blockIdx.x;
    const int b  = blockIdx.y;
    const int R  = c / 5, C = c - R * 5;
    const int t  = threadIdx.x;
    const int lane = t & 63;
    const int wav  = t >> 6;           // 0..7
    const int ln   = lane & 15;
    const int quad = lane >> 4;
    const float* Fbase = F + (size_t)b * CCH * 6400;

    auto dmaW = [&](int ks, int buf) {
        short* Wb = buf ? Wb1 : Wb0;
#pragma unroll
        for (int m = 0; m < 2; ++m) {
            const int k = wav * 2 + m;                      // 0..15
            const short* g = wp + (size_t)ks * 8192 + k * 512 + lane * 8;
            dma16(g, Wb + k * 512);                         // lane*16B appended by HW
        }
    };
    auto dmaF = [&](int ks, int buf) {
        float* Fb = buf ? Fb1 : Fb0;
#pragma unroll
        for (int m = 0; m < 2; ++m) {
            const int k = wav * 2 + m;                      // ch pair {2k, 2k+1}
            const int chl = 2 * k + (lane >> 5);
            const int px4 = (lane & 31) * 4;
            const int gpx = (8 * R + (px4 >> 4)) * 80 + 16 * C + (px4 & 15);
            const float* g = Fbase + (size_t)(ks * 32 + chl) * 6400 + gpx;
            dma16(g, Fb + k * 256);                         // 2 ch rows per instr
        }
    };

    float4_ acc[16];
#pragma unroll
    for (int i = 0; i < 16; ++i) acc[i] = (float4_){0.f, 0.f, 0.f, 0.f};

    const int pxme = wav * 16 + ln;    // this lane's pixel 0..127

    dmaW(0, 0); dmaF(0, 0);
    for (int ks = 0; ks < 8; ++ks) {
        __syncthreads();               // drains DMA(ks); protects buf[(ks+1)&1] reuse
        if (ks < 7) { dmaW(ks + 1, (ks + 1) & 1); dmaF(ks + 1, (ks + 1) & 1); }
        const short* Wl = (ks & 1) ? Wb1 : Wb0;
        const float* Fl = (ks & 1) ? Fb1 : Fb0;
        short8 bfrag;
#pragma unroll
        for (int j = 0; j < 8; ++j)
            bfrag[j] = f2bf(Fl[(quad * 8 + j) * 128 + pxme]);
#pragma unroll
        for (int mt = 0; mt < 16; ++mt) {
            short8 afrag = *(const short8*)(Wl + mt * 512 + lane * 8);
            acc[mt] = __builtin_amdgcn_mfma_f32_16x16x32_bf16(afrag, bfrag, acc[mt], 0, 0, 0);
        }
    }

    // Bias + per-pixel norm. C/D layout (validated): col(px)=lane&15, row(ch)=quad*4+r.
    float ss = 0.f;
#pragma unroll
    for (int mt = 0; mt < 16; ++mt) {
        float4_ bv = *(const float4_*)(bias + mt * 16 + quad * 4);
#pragma unroll
        for (int r = 0; r < 4; ++r) { float v = acc[mt][r] + bv[r]; acc[mt][r] = v; ss += v * v; }
    }
    ss += __shfl_xor(ss, 16);
    ss += __shfl_xor(ss, 32);
    const float inv = 1.f / sqrtf(fmaxf(ss, 1e-24f));

    __syncthreads();   // S1/S2/S3 alias the K-loop buffers

    // Stage coarse unit vectors (all reads coalesced 32-B per thread).
    {   // u1: 32 px (4 rows x 8 cols)
        const int p1 = t >> 4, ck = (t & 15) * 16;
        const int lr = p1 >> 3, lc = p1 & 7;
        const short* src = u1 + ((size_t)(b * 1600 + (4 * R + lr) * 40 + 8 * C + lc)) * CCH + ck;
        *(short8*)(&S1[p1 * 256 + ck])     = *(const short8*)src;
        *(short8*)(&S1[p1 * 256 + ck + 8]) = *(const short8*)(src + 8);
    }
    if (t < 128) {   // u2: 8 px (2 rows x 4 cols)
        const int p2 = t >> 4, ck = (t & 15) * 16;
        const int lr = p2 >> 2, lc = p2 & 3;
        const short* src = u2 + ((size_t)(b * 400 + (2 * R + lr) * 20 + 4 * C + lc)) * CCH + ck;
        *(short8*)(&S2[p2 * 256 + ck])     = *(const short8*)src;
        *(short8*)(&S2[p2 * 256 + ck + 8]) = *(const short8*)(src + 8);
    }
    if (t < 32) {    // u3: 2 px (1 row x 2 cols)
        const int p3 = t >> 4, ck = (t & 15) * 16;
        const short* src = u3 + ((size_t)(b * 100 + R * 10 + 2 * C + p3)) * CCH + ck;
        *(short8*)(&S3[p3 * 256 + ck])     = *(const short8*)src;
        *(short8*)(&S3[p3 * 256 + ck + 8]) = *(const short8*)(src + 8);
    }
    __syncthreads();

    // Fine dots: px (pr,pc) = (pxme>>4, pxme&15); this lane's 64 ch = mt*16+quad*4+r.
    const int pr = pxme >> 4, pc = pxme & 15;
    const int c1l = (pr >> 1) * 8 + (pc >> 1);
    const int c2l = (pr >> 2) * 4 + (pc >> 2);
    const int c3l = pc >> 3;
    float d01 = 0.f, d02 = 0.f, d03 = 0.f;
#pragma unroll
    for (int mt = 0; mt < 16; ++mt) {
        const int ch = mt * 16 + quad * 4;
        short4_ v1 = *(const short4_*)(&S1[c1l * 256 + ch]);
        short4_ v2 = *(const short4_*)(&S2[c2l * 256 + ch]);
        short4_ v3 = *(const short4_*)(&S3[c3l * 256 + ch]);
#pragma unroll
        for (int r = 0; r < 4; ++r) {
            float a = acc[mt][r] * inv;
            d01 += a * bf2f(v1[r]);
            d02 += a * bf2f(v2[r]);
            d03 += a * bf2f(v3[r]);
        }
    }
    {
        float vals[3] = {d01, d02, d03};
#pragma unroll
        for (int p = 0; p < 3; ++p) {
            float v = vals[p];
            v += __shfl_xor(v, 1);  v += __shfl_xor(v, 2);  v += __shfl_xor(v, 4);
            v += __shfl_xor(v, 8);  v += __shfl_xor(v, 16); v += __shfl_xor(v, 32);
            if (lane == 0) redF[wav * 3 + p] = v;
        }
    }

    // Coarse dots. Waves 0,1: d12/d13 per u1 px (32 px, 4 lanes each, 64 ch per lane).
    if (wav < 2) {
        const int p1 = wav * 16 + (lane >> 2);   // 0..31
        const int q  = lane & 3;
        const int lr = p1 >> 3, lc = p1 & 7;
        const int par2 = (lr >> 1) * 4 + (lc >> 1);
        const int par3 = lc >> 2;
        float e12 = 0.f, e13 = 0.f;
#pragma unroll
        for (int k = 0; k < 16; ++k) {
            short4_ a1 = *(const short4_*)(&S1[p1 * 256 + q * 64 + k * 4]);
            short4_ a2 = *(const short4_*)(&S2[par2 * 256 + q * 64 + k * 4]);
            short4_ a3 = *(const short4_*)(&S3[par3 * 256 + q * 64 + k * 4]);
#pragma unroll
            for (int r = 0; r < 4; ++r) {
                float x1 = bf2f(a1[r]);
                e12 += x1 * bf2f(a2[r]);
                e13 += x1 * bf2f(a3[r]);
            }
        }
        float ev[2] = {e12, e13};
#pragma unroll
        for (int p = 0; p < 2; ++p) {
            float v = ev[p];
            v += __shfl_xor(v, 1);  v += __shfl_xor(v, 2);  v += __shfl_xor(v, 4);
            v += __shfl_xor(v, 8);  v += __shfl_xor(v, 16); v += __shfl_xor(v, 32);
            if (lane == 0) redC[wav * 2 + p] = v;
        }
    } else if (wav == 2) {   // d23 per u2 px (8 px, 4 lanes each)
        float e23 = 0.f;
        if (lane < 32) {
            const int p2 = lane >> 2;
            const int q  = lane & 3;
            const int par3 = (p2 & 3) >> 1;
#pragma unroll
            for (int k = 0; k < 16; ++k) {
                short4_ a2 = *(const short4_*)(&S2[p2 * 256 + q * 64 + k * 4]);
                short4_ a3 = *(const short4_*)(&S3[par3 * 256 + q * 64 + k * 4]);
#pragma unroll
                for (int r = 0; r < 4; ++r) e23 += bf2f(a2[r]) * bf2f(a3[r]);
            }
        }
        e23 += __shfl_xor(e23, 1);  e23 += __shfl_xor(e23, 2);  e23 += __shfl_xor(e23, 4);
        e23 += __shfl_xor(e23, 8);  e23 += __shfl_xor(e23, 16); e23 += __shfl_xor(e23, 32);
        if (lane == 0) redC[4] = e23;
    }
    __syncthreads();

    if (t < 6) {
        float v;
        if (t < 3) {
            v = 0.f;
#pragma unroll
            for (int w = 0; w < 8; ++w) v += redF[w * 3 + t];
        } else if (t == 3) v = redC[0] + redC[2];       // d12
        else if (t == 4)   v = redC[1] + redC[3];       // d13
        else               v = redC[4];                 // d23
        partial[((size_t)b * 6 + t) * 50 + c] = v;
    }
}

// ---------- Softmax over j for each (b,i) row (sums 50 cell partials) ----------
__global__ void softmax4(const float* __restrict__ partial, float* __restrict__ out) {
    int t = threadIdx.x;
    if (t >= 128) return;
    int b = t >> 4, i = (t >> 2) & 3, j = t & 3;
    float a[4];
#pragma unroll
    for (int jj = 0; jj < 4; ++jj) {
        if (jj == i) { a[jj] = 1.0f; continue; }
        int lo = i < jj ? i : jj;
        int hi = i < jj ? jj : i;
        int pidx;
        if (lo == 0) pidx = hi - 1;          // (0,1)=0 (0,2)=1 (0,3)=2
        else if (lo == 1) pidx = 1 + hi;     // (1,2)=3 (1,3)=4
        else pidx = 5;                       // (2,3)=5
        const float* pp = partial + ((size_t)b * 6 + pidx) * 50;
        float s = 0.f;
        for (int k = 0; k < 50; ++k) s += pp[k];
        int rf = 80 >> lo;
        a[jj] = s / (float)(rf * rf);
    }
    float m = fmaxf(fmaxf(a[0], a[1]), fmaxf(a[2], a[3]));
    float e0 = expf(a[0] - m), e1 = expf(a[1] - m), e2 = expf(a[2] - m), e3 = expf(a[3] - m);
    float sum = e0 + e1 + e2 + e3;
    float ev = (j == 0) ? e0 : (j == 1) ? e1 : (j == 2) ? e2 : e3;
    out[t] = ev / sum;
}

extern "C" void kernel_launch(void* const* d_in, const int* in_sizes, int n_in,
                              void* d_out, int out_size, void* d_ws, size_t ws_size,
                              hipStream_t stream) {
    // setup_inputs dict insertion order: f0,w0,b0, f1,w1,b1, f2,w2,b2, f3,w3,b3
    const float* f[4]  = {(const float*)d_in[0], (const float*)d_in[3],
                          (const float*)d_in[6], (const float*)d_in[9]};
    const float* w[4]  = {(const float*)d_in[1], (const float*)d_in[4],
                          (const float*)d_in[7], (const float*)d_in[10]};
    const float* bs[4] = {(const float*)d_in[2], (const float*)d_in[5],
                          (const float*)d_in[8], (const float*)d_in[11]};

    char* ws = (char*)d_ws;
    size_t off = 0;
    short* u1 = (short*)(ws + off); off += (size_t)8 * CCH * 1600 * sizeof(short);
    short* u2 = (short*)(ws + off); off += (size_t)8 * CCH * 400  * sizeof(short);
    short* u3 = (short*)(ws + off); off += (size_t)8 * CCH * 100  * sizeof(short);
    short* wp = (short*)(ws + off); off += (size_t)65536 * sizeof(short);
    float* partial = (float*)(ws + off);   // 8*6*50 floats

    proj_small<<<304, 256, 0, stream>>>(f[1], f[2], f[3],
                                        w[0], w[1], w[2], w[3],
                                        bs[1], bs[2], bs[3],
                                        u1, u2, u3, wp);

    proj0_dots<<<dim3(50, 8), 512, 0, stream>>>(f[0], wp, bs[0],
                                                u1, u2, u3, partial);

    softmax4<<<1, 128, 0, stream>>>(partial, (float*)d_out);
}